// Round 1
// baseline (206304.468 us; speedup 1.0000x reference)
//
#include <hip/hip_runtime.h>
#include <hip/hip_bf16.h>

#define TSTEPS 4096
#define XD 256
#define HD 2048
#define YD 256
#define KD 2304   // XD + HD
#define NWG 256
#define NT 512

// ---- LDS layout (bytes) ----
#define WU_OFF 0
#define WR_OFF (8*KD*2)            // 36864
#define WC_OFF (16*KD*2)           // 73728
#define WY_OFF (24*KD*2)           // 110592
#define V1_OFF (WY_OFF + HD*4)     // 118784  v1 = [x_t | h_{t-1}]
#define V2_OFF (V1_OFF + KD*4)     // 128000  v2 = [x_t | r]
#define RED_OFF (V2_OFF + KD*4)    // 137216  red: u[8], yp[8], bu[8], br[8], bc[8], by
#define LDS_BYTES (RED_OFF + 256)  // 137472

__device__ __forceinline__ float bflo(unsigned u){ return __uint_as_float(u << 16); }
__device__ __forceinline__ float bfhi(unsigned u){ return __uint_as_float(u & 0xffff0000u); }
__device__ __forceinline__ unsigned short f2bf(float f){
  unsigned b = __float_as_uint(f);
  b += 0x7fffu + ((b >> 16) & 1u);   // RTNE (inputs finite)
  return (unsigned short)(b >> 16);
}
__device__ __forceinline__ float sigmoidf_(float x){ return 1.0f / (1.0f + __expf(-x)); }

// Monotone-counter grid barrier: release add, relaxed spin, agent acquire fence.
// budget caps total spin iterations across the whole launch (anti-hang).
__device__ __forceinline__ void gbar(unsigned* cnt, unsigned* bstep, long* budget){
  __syncthreads();
  if (threadIdx.x == 0) {
    unsigned target = (++(*bstep)) * NWG;
    __hip_atomic_fetch_add(cnt, 1u, __ATOMIC_RELEASE, __HIP_MEMORY_SCOPE_AGENT);
    while (*budget > 0 &&
           __hip_atomic_load(cnt, __ATOMIC_RELAXED, __HIP_MEMORY_SCOPE_AGENT) < target) {
      --(*budget);
      __builtin_amdgcn_s_sleep(1);
    }
  }
  __syncthreads();
  __builtin_amdgcn_fence(__ATOMIC_ACQUIRE, "agent");
}

extern "C" __global__ void __launch_bounds__(NT)
gru_persistent(const float* __restrict__ x,  const float* __restrict__ h0,
               const float* __restrict__ Wc, const float* __restrict__ Wu,
               const float* __restrict__ Wr, const float* __restrict__ bc,
               const float* __restrict__ bu, const float* __restrict__ br,
               const float* __restrict__ Wy, const float* __restrict__ by,
               float* __restrict__ out, float* hbuf, float* rbuf, unsigned* cnt)
{
  extern __shared__ char smem[];
  unsigned short* wuS = (unsigned short*)(smem + WU_OFF);
  unsigned short* wrS = (unsigned short*)(smem + WR_OFF);
  unsigned short* wcS = (unsigned short*)(smem + WC_OFF);
  float* wyS = (float*)(smem + WY_OFF);
  float* v1  = (float*)(smem + V1_OFF);
  float* v2  = (float*)(smem + V2_OFF);
  float* red = (float*)(smem + RED_OFF);

  const int wg = blockIdx.x, tid = threadIdx.x;
  const int col0 = 8 * wg;

  // ---- one-time weight staging: WG j owns gate cols [8j,8j+8), y col j ----
  for (int idx = tid; idx < 8*KD; idx += NT) {
    int c = idx & 7, k = idx >> 3;
    size_t g = (size_t)k * HD + col0 + c;   // W is [KD, 2048] row-major
    wuS[c*KD + k] = f2bf(Wu[g]);
    wrS[c*KD + k] = f2bf(Wr[g]);
    wcS[c*KD + k] = f2bf(Wc[g]);
  }
  for (int k = tid; k < HD; k += NT) wyS[k] = Wy[(size_t)k * YD + wg];
  if (tid < 8) {
    red[16+tid] = bu[col0+tid];
    red[24+tid] = br[col0+tid];
    red[32+tid] = bc[col0+tid];
  }
  if (tid == 0) red[40] = by[wg];
  __syncthreads();

  unsigned bstep = 0;
  long budget = 8000000;   // ~2 s of spinning max, then bail (no hang)

  for (int t = 0; t < TSTEPS; ++t) {
    // load v1 = [x_t | h_{t-1}], v2 x-part
    if (tid < XD/4) {
      float4 xv = ((const float4*)(x + (size_t)t * XD))[tid];
      ((float4*)v1)[tid] = xv;
      ((float4*)v2)[tid] = xv;
    }
    const float4* hsrc = (const float4*)((t == 0) ? h0 : hbuf);
    ((float4*)(v1 + XD))[tid] = hsrc[tid];   // 512 threads * float4 = 2048 floats
    __syncthreads();

    // ---- phase 1: Lu (half-waves 0-7), Lr (half-waves 8-15); K = 2304 ----
    {
      int hw = tid >> 5, l = tid & 31, c = hw & 7;
      const unsigned short* wcol = ((hw < 8) ? wuS : wrS) + c * KD;
      float4 acc = make_float4(0.f, 0.f, 0.f, 0.f);
      #pragma unroll
      for (int i = 0; i < KD/128; ++i) {       // 18 iters, 4 MACs each
        int k = 4 * (l + 32 * i);
        float4 vv = *(const float4*)(v1 + k);
        uint2  wq = *(const uint2*)(wcol + k);
        acc.x = fmaf(vv.x, bflo(wq.x), acc.x);
        acc.y = fmaf(vv.y, bfhi(wq.x), acc.y);
        acc.z = fmaf(vv.z, bflo(wq.y), acc.z);
        acc.w = fmaf(vv.w, bfhi(wq.y), acc.w);
      }
      float s = (acc.x + acc.y) + (acc.z + acc.w);
      s += __shfl_xor(s, 16); s += __shfl_xor(s, 8); s += __shfl_xor(s, 4);
      s += __shfl_xor(s, 2);  s += __shfl_xor(s, 1);
      if (l == 0) {
        if (hw < 8) red[c] = sigmoidf_(s + red[16+c]);                       // u gate
        else rbuf[col0 + c] = sigmoidf_(s + red[24+c]) * v1[XD + col0 + c];  // r*h
      }
    }
    gbar(cnt, &bstep, &budget);   // B1: r fully published

    // ---- phase 2: candidate c (wave w -> col w) + y[t-1] partials ----
    ((float4*)(v2 + XD))[tid] = ((const float4*)rbuf)[tid];
    __syncthreads();
    {
      int w = tid >> 6, l6 = tid & 63;
      const unsigned short* ccol = wcS + w * KD;
      float4 acc = make_float4(0.f, 0.f, 0.f, 0.f);
      #pragma unroll
      for (int i = 0; i < KD/256; ++i) {       // 9 iters
        int k = 4 * (l6 + 64 * i);
        float4 vv = *(const float4*)(v2 + k);
        uint2  wq = *(const uint2*)(ccol + k);
        acc.x = fmaf(vv.x, bflo(wq.x), acc.x);
        acc.y = fmaf(vv.y, bfhi(wq.x), acc.y);
        acc.z = fmaf(vv.z, bflo(wq.y), acc.z);
        acc.w = fmaf(vv.w, bfhi(wq.y), acc.w);
      }
      float s = (acc.x + acc.y) + (acc.z + acc.w);
      s += __shfl_xor(s, 32); s += __shfl_xor(s, 16); s += __shfl_xor(s, 8);
      s += __shfl_xor(s, 4);  s += __shfl_xor(s, 2);  s += __shfl_xor(s, 1);

      // y[t-1] = h_{t-1} @ Wy[:,wg] : wave w covers k in [256w, 256w+256)
      int k = 256 * w + 4 * l6;
      float4 hv  = *(const float4*)(v1 + XD + k);
      float4 wy4 = *(const float4*)(wyS + k);
      float ys = fmaf(hv.x, wy4.x, fmaf(hv.y, wy4.y, fmaf(hv.z, wy4.z, hv.w * wy4.w)));
      ys += __shfl_xor(ys, 32); ys += __shfl_xor(ys, 16); ys += __shfl_xor(ys, 8);
      ys += __shfl_xor(ys, 4);  ys += __shfl_xor(ys, 2);  ys += __shfl_xor(ys, 1);

      if (l6 == 0) {
        red[8 + w] = ys;
        float cc = tanhf(s + red[32 + w]);
        float u  = red[w];
        float hp = v1[XD + col0 + w];
        hbuf[col0 + w] = cc * u + hp * (1.0f - u);   // h_t slice
      }
    }
    __syncthreads();
    if (tid == 0 && t > 0) {
      float y = red[8]+red[9]+red[10]+red[11]+red[12]+red[13]+red[14]+red[15] + red[40];
      out[(size_t)(t-1) * YD + wg] = y;
    }
    gbar(cnt, &bstep, &budget);   // B2: h_t fully published
  }

  // ---- epilogue: y[T-1] and h_fin ----
  ((float4*)(v1 + XD))[tid] = ((const float4*)hbuf)[tid];
  __syncthreads();
  {
    int w = tid >> 6, l6 = tid & 63;
    int k = 256 * w + 4 * l6;
    float4 hv  = *(const float4*)(v1 + XD + k);
    float4 wy4 = *(const float4*)(wyS + k);
    float ys = fmaf(hv.x, wy4.x, fmaf(hv.y, wy4.y, fmaf(hv.z, wy4.z, hv.w * wy4.w)));
    ys += __shfl_xor(ys, 32); ys += __shfl_xor(ys, 16); ys += __shfl_xor(ys, 8);
    ys += __shfl_xor(ys, 4);  ys += __shfl_xor(ys, 2);  ys += __shfl_xor(ys, 1);
    if (l6 == 0) red[8 + w] = ys;
  }
  __syncthreads();
  if (tid == 0) {
    float y = red[8]+red[9]+red[10]+red[11]+red[12]+red[13]+red[14]+red[15] + red[40];
    out[(size_t)(TSTEPS-1) * YD + wg] = y;
  }
  if (tid < 8) out[(size_t)TSTEPS * YD + col0 + tid] = hbuf[col0 + tid];
}

extern "C" void kernel_launch(void* const* d_in, const int* in_sizes, int n_in,
                              void* d_out, int out_size, void* d_ws, size_t ws_size,
                              hipStream_t stream) {
  const float* x  = (const float*)d_in[0];
  const float* h0 = (const float*)d_in[1];
  const float* Wc = (const float*)d_in[2];
  const float* Wu = (const float*)d_in[3];
  const float* Wr = (const float*)d_in[4];
  const float* bc = (const float*)d_in[5];
  const float* bu = (const float*)d_in[6];
  const float* br = (const float*)d_in[7];
  const float* Wy = (const float*)d_in[8];
  const float* by = (const float*)d_in[9];
  float* out = (float*)d_out;

  unsigned* cnt = (unsigned*)d_ws;                       // barrier counter
  float* hbuf = (float*)((char*)d_ws + 256);             // h exchange (8 KB)
  float* rbuf = (float*)((char*)d_ws + 256 + HD*4);      // r exchange (8 KB)

  // >64 KB dynamic LDS on gfx950 (160 KB/CU). Idempotent; capture-safe (not a stream op).
  hipFuncSetAttribute((const void*)gru_persistent,
                      hipFuncAttributeMaxDynamicSharedMemorySize, LDS_BYTES);
  hipMemsetAsync(d_ws, 0, 64, stream);                   // zero barrier counter
  gru_persistent<<<dim3(NWG), dim3(NT), LDS_BYTES, stream>>>(
      x, h0, Wc, Wu, Wr, bc, bu, br, Wy, by, out, hbuf, rbuf, cnt);
}

// Round 2
// 24725.084 us; speedup vs baseline: 8.3439x; 8.3439x over previous
//
#include <hip/hip_runtime.h>
#include <hip/hip_bf16.h>

#define TSTEPS 4096
#define XD 256
#define HD 2048
#define YD 256
#define KD 2304   // XD + HD
#define NWG 256
#define NT 512

// ---- LDS layout (bytes) ----
#define WU_OFF 0
#define WR_OFF (8*KD*2)            // 36864
#define WC_OFF (16*KD*2)           // 73728
#define WY_OFF (24*KD*2)           // 110592
#define V1_OFF (WY_OFF + HD*4)     // 118784  v1 = [x_t | h_{t-1}]
#define V2_OFF (V1_OFF + KD*4)     // 128000  v2 = [x_t | r]
#define RED_OFF (V2_OFF + KD*4)    // 137216  red: u[8], yp[8], bu[8], br[8], bc[8], by
#define LDS_BYTES (RED_OFF + 256)  // 137472

// ---- workspace layout (u32 indices; 64B line spacing for flags/go) ----
#define FLAGS_U32 0                 // flags[w] at w*16          (256 lines, 16 KB)
#define GO_U32    4096              // go[i]    at 4096 + i*16   (8 lines, 512 B)
#define HBUF_OFF  17408             // 8 KB, 128-aligned
#define RBUF_OFF  25600             // 8 KB
#define WS_ZERO_BYTES 16896         // flags + go

__device__ __forceinline__ float bflo(unsigned u){ return __uint_as_float(u << 16); }
__device__ __forceinline__ float bfhi(unsigned u){ return __uint_as_float(u & 0xffff0000u); }
__device__ __forceinline__ unsigned short f2bf(float f){
  unsigned b = __float_as_uint(f);
  b += 0x7fffu + ((b >> 16) & 1u);   // RTNE (inputs finite)
  return (unsigned short)(b >> 16);
}
__device__ __forceinline__ float sigmoidf_(float x){ return 1.0f / (1.0f + __expf(-x)); }

// Fence-free master-gather grid barrier.
// Producers publish data with agent-scope relaxed (cache-bypass) atomic stores;
// __syncthreads() drains vmcnt(0) so data is at LLC before the flag store.
// Consumers read exchange buffers with agent-scope relaxed atomic loads (always
// fresh from LLC) -> no buffer_inv / buffer_wbl2 on the hot path at all.
__device__ __forceinline__ void gbar(unsigned* wsu, unsigned epoch, long* budget){
  __syncthreads();                                   // drains vmcnt(0) per wave
  if (blockIdx.x == 0) {
    int tid = threadIdx.x;
    if (tid > 0 && tid < NWG) {
      unsigned* f = wsu + FLAGS_U32 + tid * 16;
      while (*budget > 0 &&
             __hip_atomic_load(f, __ATOMIC_RELAXED, __HIP_MEMORY_SCOPE_AGENT) < epoch) {
        --(*budget);
        __builtin_amdgcn_s_sleep(2);
      }
    }
    __syncthreads();                                 // all flags seen by WG0
    if (tid < 8)
      __hip_atomic_store(wsu + GO_U32 + tid * 16, epoch,
                         __ATOMIC_RELAXED, __HIP_MEMORY_SCOPE_AGENT);
  } else {
    if (threadIdx.x == 0) {
      __hip_atomic_store(wsu + FLAGS_U32 + blockIdx.x * 16, epoch,
                         __ATOMIC_RELAXED, __HIP_MEMORY_SCOPE_AGENT);
      unsigned* g = wsu + GO_U32 + (blockIdx.x & 7) * 16;
      while (*budget > 0 &&
             __hip_atomic_load(g, __ATOMIC_RELAXED, __HIP_MEMORY_SCOPE_AGENT) < epoch) {
        --(*budget);
        __builtin_amdgcn_s_sleep(2);
      }
    }
    __syncthreads();
  }
}

__device__ __forceinline__ unsigned long long gld64(const unsigned long long* p){
  return __hip_atomic_load(p, __ATOMIC_RELAXED, __HIP_MEMORY_SCOPE_AGENT);
}
__device__ __forceinline__ void gst32f(float* p, float v){
  __hip_atomic_store(p, v, __ATOMIC_RELAXED, __HIP_MEMORY_SCOPE_AGENT);
}

extern "C" __global__ void __launch_bounds__(NT)
gru_persistent(const float* __restrict__ x,  const float* __restrict__ h0,
               const float* __restrict__ Wc, const float* __restrict__ Wu,
               const float* __restrict__ Wr, const float* __restrict__ bc,
               const float* __restrict__ bu, const float* __restrict__ br,
               const float* __restrict__ Wy, const float* __restrict__ by,
               float* __restrict__ out, unsigned* wsu)
{
  extern __shared__ char smem[];
  unsigned short* wuS = (unsigned short*)(smem + WU_OFF);
  unsigned short* wrS = (unsigned short*)(smem + WR_OFF);
  unsigned short* wcS = (unsigned short*)(smem + WC_OFF);
  float* wyS = (float*)(smem + WY_OFF);
  float* v1  = (float*)(smem + V1_OFF);
  float* v2  = (float*)(smem + V2_OFF);
  float* red = (float*)(smem + RED_OFF);

  float* hbuf = (float*)((char*)wsu + HBUF_OFF);
  float* rbuf = (float*)((char*)wsu + RBUF_OFF);

  const int wg = blockIdx.x, tid = threadIdx.x;
  const int col0 = 8 * wg;

  // ---- one-time weight staging: WG j owns gate cols [8j,8j+8), y col j ----
  for (int idx = tid; idx < 8*KD; idx += NT) {
    int c = idx & 7, k = idx >> 3;
    size_t g = (size_t)k * HD + col0 + c;   // W is [KD, 2048] row-major
    wuS[c*KD + k] = f2bf(Wu[g]);
    wrS[c*KD + k] = f2bf(Wr[g]);
    wcS[c*KD + k] = f2bf(Wc[g]);
  }
  for (int k = tid; k < HD; k += NT) wyS[k] = Wy[(size_t)k * YD + wg];
  if (tid < 8) {
    red[16+tid] = bu[col0+tid];
    red[24+tid] = br[col0+tid];
    red[32+tid] = bc[col0+tid];
  }
  if (tid == 0) red[40] = by[wg];
  __syncthreads();

  long budget = 50000000;   // anti-hang spin cap (~3 s worst case)
  unsigned epoch = 0;

  for (int t = 0; t < TSTEPS; ++t) {
    // load v1 = [x_t | h_{t-1}], v2 x-part
    if (tid < XD/4) {
      float4 xv = ((const float4*)(x + (size_t)t * XD))[tid];
      ((float4*)v1)[tid] = xv;
      ((float4*)v2)[tid] = xv;
    }
    if (t == 0) {
      ((float4*)(v1 + XD))[tid] = ((const float4*)h0)[tid];
    } else {
      const unsigned long long* hb = (const unsigned long long*)hbuf;
      unsigned long long a = gld64(hb + 2*tid);
      unsigned long long b = gld64(hb + 2*tid + 1);
      ((unsigned long long*)(v1 + XD))[2*tid]     = a;
      ((unsigned long long*)(v1 + XD))[2*tid + 1] = b;
    }
    __syncthreads();

    // ---- phase 1: Lu (half-waves 0-7), Lr (half-waves 8-15); K = 2304 ----
    {
      int hw = tid >> 5, l = tid & 31, c = hw & 7;
      const unsigned short* wcol = ((hw < 8) ? wuS : wrS) + c * KD;
      float4 acc = make_float4(0.f, 0.f, 0.f, 0.f);
      #pragma unroll
      for (int i = 0; i < KD/128; ++i) {       // 18 iters, 4 MACs each
        int k = 4 * (l + 32 * i);
        float4 vv = *(const float4*)(v1 + k);
        uint2  wq = *(const uint2*)(wcol + k);
        acc.x = fmaf(vv.x, bflo(wq.x), acc.x);
        acc.y = fmaf(vv.y, bfhi(wq.x), acc.y);
        acc.z = fmaf(vv.z, bflo(wq.y), acc.z);
        acc.w = fmaf(vv.w, bfhi(wq.y), acc.w);
      }
      float s = (acc.x + acc.y) + (acc.z + acc.w);
      s += __shfl_xor(s, 16); s += __shfl_xor(s, 8); s += __shfl_xor(s, 4);
      s += __shfl_xor(s, 2);  s += __shfl_xor(s, 1);
      if (l == 0) {
        if (hw < 8) red[c] = sigmoidf_(s + red[16+c]);                          // u gate
        else gst32f(rbuf + col0 + c, sigmoidf_(s + red[24+c]) * v1[XD+col0+c]); // r*h
      }
    }
    gbar(wsu, ++epoch, &budget);   // B1: r fully published

    // ---- phase 2: candidate c (wave w -> col w) + y[t-1] partials ----
    {
      const unsigned long long* rb = (const unsigned long long*)rbuf;
      unsigned long long a = gld64(rb + 2*tid);
      unsigned long long b = gld64(rb + 2*tid + 1);
      ((unsigned long long*)(v2 + XD))[2*tid]     = a;
      ((unsigned long long*)(v2 + XD))[2*tid + 1] = b;
    }
    __syncthreads();
    {
      int w = tid >> 6, l6 = tid & 63;
      const unsigned short* ccol = wcS + w * KD;
      float4 acc = make_float4(0.f, 0.f, 0.f, 0.f);
      #pragma unroll
      for (int i = 0; i < KD/256; ++i) {       // 9 iters
        int k = 4 * (l6 + 64 * i);
        float4 vv = *(const float4*)(v2 + k);
        uint2  wq = *(const uint2*)(ccol + k);
        acc.x = fmaf(vv.x, bflo(wq.x), acc.x);
        acc.y = fmaf(vv.y, bfhi(wq.x), acc.y);
        acc.z = fmaf(vv.z, bflo(wq.y), acc.z);
        acc.w = fmaf(vv.w, bfhi(wq.y), acc.w);
      }
      float s = (acc.x + acc.y) + (acc.z + acc.w);
      s += __shfl_xor(s, 32); s += __shfl_xor(s, 16); s += __shfl_xor(s, 8);
      s += __shfl_xor(s, 4);  s += __shfl_xor(s, 2);  s += __shfl_xor(s, 1);

      // y[t-1] = h_{t-1} @ Wy[:,wg] : wave w covers k in [256w, 256w+256)
      int k = 256 * w + 4 * l6;
      float4 hv  = *(const float4*)(v1 + XD + k);
      float4 wy4 = *(const float4*)(wyS + k);
      float ys = fmaf(hv.x, wy4.x, fmaf(hv.y, wy4.y, fmaf(hv.z, wy4.z, hv.w * wy4.w)));
      ys += __shfl_xor(ys, 32); ys += __shfl_xor(ys, 16); ys += __shfl_xor(ys, 8);
      ys += __shfl_xor(ys, 4);  ys += __shfl_xor(ys, 2);  ys += __shfl_xor(ys, 1);

      if (l6 == 0) {
        red[8 + w] = ys;
        float cc = tanhf(s + red[32 + w]);
        float u  = red[w];
        float hp = v1[XD + col0 + w];
        gst32f(hbuf + col0 + w, cc * u + hp * (1.0f - u));   // h_t slice
      }
    }
    __syncthreads();
    if (tid == 0 && t > 0) {
      float y = red[8]+red[9]+red[10]+red[11]+red[12]+red[13]+red[14]+red[15] + red[40];
      out[(size_t)(t-1) * YD + wg] = y;
    }
    gbar(wsu, ++epoch, &budget);   // B2: h_t fully published
  }

  // ---- epilogue: y[T-1] and h_fin ----
  {
    const unsigned long long* hb = (const unsigned long long*)hbuf;
    unsigned long long a = gld64(hb + 2*tid);
    unsigned long long b = gld64(hb + 2*tid + 1);
    ((unsigned long long*)(v1 + XD))[2*tid]     = a;
    ((unsigned long long*)(v1 + XD))[2*tid + 1] = b;
  }
  __syncthreads();
  {
    int w = tid >> 6, l6 = tid & 63;
    int k = 256 * w + 4 * l6;
    float4 hv  = *(const float4*)(v1 + XD + k);
    float4 wy4 = *(const float4*)(wyS + k);
    float ys = fmaf(hv.x, wy4.x, fmaf(hv.y, wy4.y, fmaf(hv.z, wy4.z, hv.w * wy4.w)));
    ys += __shfl_xor(ys, 32); ys += __shfl_xor(ys, 16); ys += __shfl_xor(ys, 8);
    ys += __shfl_xor(ys, 4);  ys += __shfl_xor(ys, 2);  ys += __shfl_xor(ys, 1);
    if (l6 == 0) red[8 + w] = ys;
  }
  __syncthreads();
  if (tid == 0) {
    float y = red[8]+red[9]+red[10]+red[11]+red[12]+red[13]+red[14]+red[15] + red[40];
    out[(size_t)(TSTEPS-1) * YD + wg] = y;
  }
  if (tid < 8) out[(size_t)TSTEPS * YD + col0 + tid] = v1[XD + col0 + tid];
}

extern "C" void kernel_launch(void* const* d_in, const int* in_sizes, int n_in,
                              void* d_out, int out_size, void* d_ws, size_t ws_size,
                              hipStream_t stream) {
  const float* x  = (const float*)d_in[0];
  const float* h0 = (const float*)d_in[1];
  const float* Wc = (const float*)d_in[2];
  const float* Wu = (const float*)d_in[3];
  const float* Wr = (const float*)d_in[4];
  const float* bc = (const float*)d_in[5];
  const float* bu = (const float*)d_in[6];
  const float* br = (const float*)d_in[7];
  const float* Wy = (const float*)d_in[8];
  const float* by = (const float*)d_in[9];
  float* out = (float*)d_out;
  unsigned* wsu = (unsigned*)d_ws;

  // >64 KB dynamic LDS on gfx950 (160 KB/CU). Idempotent; capture-safe.
  hipFuncSetAttribute((const void*)gru_persistent,
                      hipFuncAttributeMaxDynamicSharedMemorySize, LDS_BYTES);
  hipMemsetAsync(d_ws, 0, WS_ZERO_BYTES, stream);        // zero flags + go lines
  gru_persistent<<<dim3(NWG), dim3(NT), LDS_BYTES, stream>>>(
      x, h0, Wc, Wu, Wr, bc, bu, br, Wy, by, out, wsu);
}